// Round 14
// baseline (149.421 us; speedup 1.0000x reference)
//
#include <hip/hip_runtime.h>
#include <stdint.h>

#define BATCH   131072
#define HASHLEN 64
#define HID     180
#define OUT     300

#define BM      64        // rows per block
#define NT      128       // 2 waves; each wave owns 32 rows (2 row-tiles)
#define NTILE2  19        // ceil(300/16)

// fragment counts in ws
#define WH_FRAGS  (12 * 2 * 64)             // 1536
#define WM_FRAGS  (NTILE2 * 6 * 64)         // 7296
#define TOT_FRAGS (WH_FRAGS + 2 * WM_FRAGS) // 16128
#define WS_NEEDED ((size_t)TOT_FRAGS * 16)  // 258048 B

typedef short bf16x8 __attribute__((ext_vector_type(8)));
typedef float f32x4  __attribute__((ext_vector_type(4)));

// fast hw ops
#define FAST_SQRT(x) __builtin_amdgcn_sqrtf(x)   // v_sqrt_f32
#define ROTL(x, r) __builtin_amdgcn_alignbit((x), (x), 32u - (r))

// Threefry-2x32/20, key (0,42), counter (0,ctr), bits = x0^x1 (verified R0/R2).
__device__ __forceinline__ unsigned threefry_bits(unsigned ctr) {
  const unsigned ks0 = 0u;
  const unsigned ks1 = 42u;
  const unsigned ks2 = 0x1BD11BDAu ^ 0u ^ 42u;
  unsigned x0 = ks0;
  unsigned x1 = ctr + ks1;
#define TF_R(r) { x0 += x1; x1 = ROTL(x1, r); x1 ^= x0; }
  TF_R(13u) TF_R(15u) TF_R(26u) TF_R(6u)
  x0 += ks1; x1 += ks2 + 1u;
  TF_R(17u) TF_R(29u) TF_R(16u) TF_R(24u)
  x0 += ks2; x1 += ks0 + 2u;
  TF_R(13u) TF_R(15u) TF_R(26u) TF_R(6u)
  x0 += ks0; x1 += ks1 + 3u;
  TF_R(17u) TF_R(29u) TF_R(16u) TF_R(24u)
  x0 += ks1; x1 += ks2 + 4u;
  TF_R(13u) TF_R(15u) TF_R(26u) TF_R(6u)
  x0 += ks2; x1 += ks0 + 5u;
#undef TF_R
  return x0 ^ x1;
}

// sqrt(2)*erfinv(x), XLA-Giles polynomial in log2 domain (verified R5).
__device__ __forceinline__ float poly_low_sqrt2(float zz) {
  float p = 2.11772e-09f;
  p = fmaf(p, zz, 3.73196e-08f);
  p = fmaf(p, zz, -5.52613e-07f);
  p = fmaf(p, zz, -9.93702e-07f);
  p = fmaf(p, zz, 7.13551e-05f);
  p = fmaf(p, zz, -5.90464e-04f);
  p = fmaf(p, zz, -2.83858e-03f);
  p = fmaf(p, zz, 0.24177160f);
  p = fmaf(p, zz, 2.1233136f);
  return p;
}
__device__ __forceinline__ float poly_high_sqrt2(float v) {
  float p = -6.53600e-05f;
  p = fmaf(p, v, 3.95852e-05f);
  p = fmaf(p, v, 6.35506e-04f);
  p = fmaf(p, v, -2.07827e-03f);
  p = fmaf(p, v, 3.89984e-03f);
  p = fmaf(p, v, -6.22117e-03f);
  p = fmaf(p, v, 9.25254e-03f);
  p = fmaf(p, v, 1.1793807f);
  p = fmaf(p, v, 4.0064340f);
  return p;
}

// full eps from threefry bits (verified R5 path)
__device__ __forceinline__ float eps_from_bits(uint32_t bits) {
  float f = __uint_as_float((bits >> 9) | 0x3F800000u) - 1.0f;
  const float LO = -0.99999994f;
  float u = fmaxf(LO, fmaf(f, 2.0f, LO));
  float t = fmaf(-u, u, 1.0f);
  float z = -__log2f(t);
  float p = poly_low_sqrt2(z - 3.6067376f);
  if (__any(z >= 7.2134752f)) {
    float ph = poly_high_sqrt2(FAST_SQRT(z) - 3.6033669f);
    p = (z >= 7.2134752f) ? ph : p;
  }
  return p * u;
}

// fp32 -> bf16 round-to-nearest-even
__device__ __forceinline__ uint16_t f2bf(float f) {
  uint32_t u = __float_as_uint(f);
  return (uint16_t)((u + 0x7FFFu + ((u >> 16) & 1u)) >> 16);
}

// ---------------- pre-kernel: weights to MFMA fragment order ----------------
__global__ __launch_bounds__(256) void prep_weights(
    const float* __restrict__ W_h, const float* __restrict__ W_mu,
    const float* __restrict__ W_sig, uint16_t* __restrict__ ws)
{
  int f = blockIdx.x * 256 + threadIdx.x;
  if (f >= TOT_FRAGS) return;
  uint16_t vals[8];
  if (f < WH_FRAGS) {
    int nt = f >> 7, s = (f >> 6) & 1, l = f & 63;
    int row = nt * 16 + (l & 15);
    int k0  = s * 32 + (l >> 4) * 8;
#pragma unroll
    for (int j = 0; j < 8; ++j)
      vals[j] = (row < HID) ? f2bf(W_h[row * HASHLEN + k0 + j]) : (uint16_t)0;
  } else {
    int g = f - WH_FRAGS;
    const float* W = (g < WM_FRAGS) ? W_mu : W_sig;
    if (g >= WM_FRAGS) g -= WM_FRAGS;
    int gt = g / 384, s = (g >> 6) % 6, l = g & 63;
    int col = gt * 16 + (l & 15);
    int k0  = s * 32 + (l >> 4) * 8;
#pragma unroll
    for (int j = 0; j < 8; ++j) {
      int k = k0 + j;
      vals[j] = (col < OUT && k < HID) ? f2bf(W[col * HID + k]) : (uint16_t)0;
    }
  }
  uint16_t* dst = ws + (size_t)f * 8;
#pragma unroll
  for (int j = 0; j < 8; ++j) dst[j] = vals[j];
}

// epilogue over a PAIR of adjacent gt tiles: 8 outputs/lane, 8 threefry chains
__device__ __forceinline__ void epilogue8(
    f32x4 aM0, f32x4 aS0, f32x4 aM1, f32x4 aS1,
    f32x4 bm0, f32x4 bs0, f32x4 bm1, f32x4 bs1,
    uint32_t gi0, float* __restrict__ out)
{
  uint32_t bits[8];
#pragma unroll
  for (int j = 0; j < 8; ++j) {
    // cols: tile0 -> gi0+{0..3}, tile1 -> gi0+16+{0..3}
    uint32_t c = gi0 + (uint32_t)((j < 4) ? j : (12 + j));
    bits[j] = threefry_bits(c);
  }
  float xx[8], z[8], pl[8];
#pragma unroll
  for (int j = 0; j < 8; ++j) {
    float f = __uint_as_float((bits[j] >> 9) | 0x3F800000u) - 1.0f;
    const float LO = -0.99999994f;     // nextafter(-1, 0)
    float u = fmaxf(LO, fmaf(f, 2.0f, LO));
    xx[j] = u;
    float t = fmaf(-u, u, 1.0f);
    z[j] = -__log2f(t);                // v_log_f32
    pl[j] = poly_low_sqrt2(z[j] - 3.6067376f);
  }
#pragma unroll
  for (int j = 0; j < 8; ++j) {
    if (__any(z[j] >= 7.2134752f)) {
      float ph = poly_high_sqrt2(FAST_SQRT(z[j]) - 3.6033669f);
      pl[j] = (z[j] >= 7.2134752f) ? ph : pl[j];
    }
  }
  f32x4 r0, r1;
#pragma unroll
  for (int q = 0; q < 4; ++q) {
    r0[q] = fmaf(fabsf(aS0[q] + bs0[q]), pl[q] * xx[q],         aM0[q] + bm0[q]);
    r1[q] = fmaf(fabsf(aS1[q] + bs1[q]), pl[q + 4] * xx[q + 4], aM1[q] + bm1[q]);
  }
  *(f32x4*)(out + gi0)      = r0;
  *(f32x4*)(out + gi0 + 16) = r1;
}

// single-tile epilogue (tail)
__device__ __forceinline__ void epilogue4(
    f32x4 accM, f32x4 accS, f32x4 bm4, f32x4 bs4, uint32_t gi0,
    float* __restrict__ out)
{
  uint32_t bits[4];
#pragma unroll
  for (int q = 0; q < 4; ++q)
    bits[q] = threefry_bits(gi0 + (uint32_t)q);
  float xx[4], z[4], pl[4];
#pragma unroll
  for (int q = 0; q < 4; ++q) {
    float f = __uint_as_float((bits[q] >> 9) | 0x3F800000u) - 1.0f;
    const float LO = -0.99999994f;
    float u = fmaxf(LO, fmaf(f, 2.0f, LO));
    xx[q] = u;
    float t = fmaf(-u, u, 1.0f);
    z[q] = -__log2f(t);
    pl[q] = poly_low_sqrt2(z[q] - 3.6067376f);
  }
#pragma unroll
  for (int q = 0; q < 4; ++q) {
    if (__any(z[q] >= 7.2134752f)) {
      float ph = poly_high_sqrt2(FAST_SQRT(z[q]) - 3.6033669f);
      pl[q] = (z[q] >= 7.2134752f) ? ph : pl[q];
    }
  }
  f32x4 res;
#pragma unroll
  for (int q = 0; q < 4; ++q) {
    float mu  = accM[q] + bm4[q];
    float sg  = fabsf(accS[q] + bs4[q]);
    res[q] = fmaf(sg, pl[q] * xx[q], mu);
  }
  *(f32x4*)(out + gi0) = res;
}

// ---------------- main fused kernel (2 waves, 2 row-tiles/wave) -------------
__global__ __launch_bounds__(NT, 3) void fused_decoder(
    const float* __restrict__ bin,
    const uint16_t* __restrict__ ws,
    const float* __restrict__ b_h,
    const float* __restrict__ b_mu, const float* __restrict__ b_sig,
    float* __restrict__ out)
{
  __shared__ unsigned char lds[BM * 384];   // h tile [64][192] bf16, swizzled

  const int tid    = threadIdx.x;
  const int l      = tid & 63;
  const int w      = tid >> 6;              // wave 0..1
  const int lane15 = l & 15;
  const int lhi    = l >> 4;
  const int swzb   = (lane15 & 7) << 4;
  const int row0   = blockIdx.x * BM;
  const int r0     = w * 32;                // this wave's 32-row slab

  const bf16x8* wsWh = (const bf16x8*)ws;
  const bf16x8* wsWm = (const bf16x8*)ws + WH_FRAGS;
  const bf16x8* wsWs = (const bf16x8*)ws + WH_FRAGS + WM_FRAGS;

  // ---------- GEMM1 (swapped): h^T = W_h @ b^T, 2 row-tiles ----------
  {
    bf16x8 bfrag[2][2];
#pragma unroll
    for (int rt = 0; rt < 2; ++rt) {
      const float* brow = bin + (size_t)(row0 + r0 + rt * 16 + lane15) * HASHLEN;
#pragma unroll
      for (int s = 0; s < 2; ++s) {
        float4 v0 = *(const float4*)(brow + s * 32 + lhi * 8);
        float4 v1 = *(const float4*)(brow + s * 32 + lhi * 8 + 4);
        bf16x8 a;
        a[0] = (short)f2bf(v0.x); a[1] = (short)f2bf(v0.y);
        a[2] = (short)f2bf(v0.z); a[3] = (short)f2bf(v0.w);
        a[4] = (short)f2bf(v1.x); a[5] = (short)f2bf(v1.y);
        a[6] = (short)f2bf(v1.z); a[7] = (short)f2bf(v1.w);
        bfrag[rt][s] = a;
      }
    }
#pragma unroll
    for (int nt = 0; nt < 12; ++nt) {
      f32x4 acc0 = {0.f, 0.f, 0.f, 0.f};
      f32x4 acc1 = {0.f, 0.f, 0.f, 0.f};
#pragma unroll
      for (int s = 0; s < 2; ++s) {
        bf16x8 bw = wsWh[(nt * 2 + s) * 64 + l];   // shared by both row-tiles
        acc0 = __builtin_amdgcn_mfma_f32_16x16x32_bf16(bw, bfrag[0][s], acc0, 0, 0, 0);
        acc1 = __builtin_amdgcn_mfma_f32_16x16x32_bf16(bw, bfrag[1][s], acc1, 0, 0, 0);
      }
      const int k0 = nt * 16 + lhi * 4;
      f32x4 bias = {0.f, 0.f, 0.f, 0.f};
      if (k0 <= HID - 4) bias = *(const f32x4*)(b_h + k0);
      const bool ok = (k0 < HID);               // quad-uniform (HID % 4 == 0)
#pragma unroll
      for (int rt = 0; rt < 2; ++rt) {
        f32x4 acc = rt ? acc1 : acc0;
        float h0 = ok ? (acc[0] + bias[0]) : 0.0f;
        float h1 = ok ? (acc[1] + bias[1]) : 0.0f;
        float h2 = ok ? (acc[2] + bias[2]) : 0.0f;
        float h3 = ok ? (acc[3] + bias[3]) : 0.0f;
        uint2 pk;
        pk.x = (uint32_t)f2bf(h0) | ((uint32_t)f2bf(h1) << 16);
        pk.y = (uint32_t)f2bf(h2) | ((uint32_t)f2bf(h3) << 16);
        const int row = r0 + rt * 16 + lane15;
        *(uint2*)(lds + row * 384 + ((2 * k0) ^ swzb)) = pk;
      }
    }
  }
  // no barrier: h rows are wave-private; same-wave LDS ops are in-order.

  bf16x8 a2[2][6];
#pragma unroll
  for (int rt = 0; rt < 2; ++rt)
#pragma unroll
    for (int s = 0; s < 6; ++s)
      a2[rt][s] = *(const bf16x8*)(lds + (r0 + rt * 16 + lane15) * 384 +
                                   ((s * 64 + lhi * 16) ^ swzb));

  // lane output: batch row = (r0 + rt*16 + lane15), cols = gt*16 + lhi*4 + {0..3}
  const uint32_t idx0  = (uint32_t)((row0 + r0 + lane15) * OUT + lhi * 4);
  const uint32_t idx1  = idx0 + (uint32_t)(16 * OUT);

  // ---------- GEMM2: 9 tile-pairs (gt 0..17), then tail gt=18 ----------
#pragma unroll 1
  for (int gp = 0; gp < 9; ++gp) {
    const int gt0 = gp * 2;
    const int gt1 = gt0 + 1;
    // accumulators for both row-tiles
    f32x4 aM0r0 = {0.f, 0.f, 0.f, 0.f}, aS0r0 = {0.f, 0.f, 0.f, 0.f};
    f32x4 aM1r0 = {0.f, 0.f, 0.f, 0.f}, aS1r0 = {0.f, 0.f, 0.f, 0.f};
    f32x4 aM0r1 = {0.f, 0.f, 0.f, 0.f}, aS0r1 = {0.f, 0.f, 0.f, 0.f};
    f32x4 aM1r1 = {0.f, 0.f, 0.f, 0.f}, aS1r1 = {0.f, 0.f, 0.f, 0.f};
    // per (tile, matrix): load 6 frags, feed both row-tiles, frags die
#pragma unroll
    for (int s = 0; s < 6; ++s) {
      bf16x8 f = wsWm[(gt0 * 6 + s) * 64 + l];
      aM0r0 = __builtin_amdgcn_mfma_f32_16x16x32_bf16(f, a2[0][s], aM0r0, 0, 0, 0);
      aM0r1 = __builtin_amdgcn_mfma_f32_16x16x32_bf16(f, a2[1][s], aM0r1, 0, 0, 0);
    }
#pragma unroll
    for (int s = 0; s < 6; ++s) {
      bf16x8 f = wsWs[(gt0 * 6 + s) * 64 + l];
      aS0r0 = __builtin_amdgcn_mfma_f32_16x16x32_bf16(f, a2[0][s], aS0r0, 0, 0, 0);
      aS0r1 = __builtin_amdgcn_mfma_f32_16x16x32_bf16(f, a2[1][s], aS0r1, 0, 0, 0);
    }
#pragma unroll
    for (int s = 0; s < 6; ++s) {
      bf16x8 f = wsWm[(gt1 * 6 + s) * 64 + l];
      aM1r0 = __builtin_amdgcn_mfma_f32_16x16x32_bf16(f, a2[0][s], aM1r0, 0, 0, 0);
      aM1r1 = __builtin_amdgcn_mfma_f32_16x16x32_bf16(f, a2[1][s], aM1r1, 0, 0, 0);
    }
#pragma unroll
    for (int s = 0; s < 6; ++s) {
      bf16x8 f = wsWs[(gt1 * 6 + s) * 64 + l];
      aS1r0 = __builtin_amdgcn_mfma_f32_16x16x32_bf16(f, a2[0][s], aS1r0, 0, 0, 0);
      aS1r1 = __builtin_amdgcn_mfma_f32_16x16x32_bf16(f, a2[1][s], aS1r1, 0, 0, 0);
    }

    const int c0 = gt0 * 16 + lhi * 4;
    f32x4 bm0 = *(const f32x4*)(b_mu + c0);
    f32x4 bs0 = *(const f32x4*)(b_sig + c0);
    f32x4 bm1 = *(const f32x4*)(b_mu + c0 + 16);
    f32x4 bs1 = *(const f32x4*)(b_sig + c0 + 16);
    const uint32_t go = (uint32_t)(gt0 * 16);
    epilogue8(aM0r0, aS0r0, aM1r0, aS1r0, bm0, bs0, bm1, bs1, idx0 + go, out);
    epilogue8(aM0r1, aS0r1, aM1r1, aS1r1, bm0, bs0, bm1, bs1, idx1 + go, out);
  }

  // ---------- tail tile gt=18: valid iff lhi < 3 (quad-uniform) ----------
  {
    const int gt = NTILE2 - 1;
    f32x4 aMr0 = {0.f, 0.f, 0.f, 0.f}, aSr0 = {0.f, 0.f, 0.f, 0.f};
    f32x4 aMr1 = {0.f, 0.f, 0.f, 0.f}, aSr1 = {0.f, 0.f, 0.f, 0.f};
#pragma unroll
    for (int s = 0; s < 6; ++s) {
      bf16x8 fM = wsWm[(gt * 6 + s) * 64 + l];
      bf16x8 fS = wsWs[(gt * 6 + s) * 64 + l];
      aMr0 = __builtin_amdgcn_mfma_f32_16x16x32_bf16(fM, a2[0][s], aMr0, 0, 0, 0);
      aMr1 = __builtin_amdgcn_mfma_f32_16x16x32_bf16(fM, a2[1][s], aMr1, 0, 0, 0);
      aSr0 = __builtin_amdgcn_mfma_f32_16x16x32_bf16(fS, a2[0][s], aSr0, 0, 0, 0);
      aSr1 = __builtin_amdgcn_mfma_f32_16x16x32_bf16(fS, a2[1][s], aSr1, 0, 0, 0);
    }
    if (lhi < 3) {
      const int c0 = gt * 16 + lhi * 4;
      f32x4 bm4 = *(const f32x4*)(b_mu + c0);
      f32x4 bs4 = *(const f32x4*)(b_sig + c0);
      const uint32_t go = (uint32_t)(gt * 16);
      epilogue4(aMr0, aSr0, bm4, bs4, idx0 + go, out);
      epilogue4(aMr1, aSr1, bm4, bs4, idx1 + go, out);
    }
  }
}

// ---------------- fallback (no ws): R2-proven path --------------------------
#define FNT     256
#define FTILE2  19
#define FCHT    2
#define FNCH    10
#define FSH_OFF   0
#define FSH_BYTES (64 * 384)
#define FU_OFF    FSH_BYTES
#define FSB_OFF   FU_OFF
#define FSWH_OFF  (FU_OFF + 8192)
#define FSWM_OFF  FU_OFF
#define FSWS_OFF  (FU_OFF + 12288)
#define FLDS_BYTES (FSH_BYTES + 32768)

__global__ __launch_bounds__(FNT) void fused_decoder_fb(
    const float* __restrict__ bin,
    const float* __restrict__ W_h, const float* __restrict__ b_h,
    const float* __restrict__ W_mu, const float* __restrict__ b_mu,
    const float* __restrict__ W_sig, const float* __restrict__ b_sig,
    float* __restrict__ out)
{
  __shared__ unsigned char lds[FLDS_BYTES];
  const int tid = threadIdx.x;
  const int l = tid & 63, w = tid >> 6;
  const int lane15 = l & 15, lhi = l >> 4;
  const int swzb = (l & 7) << 4;
  const int row0 = blockIdx.x * BM;
  const int r0 = w * 16;
  {
    const float4* src = reinterpret_cast<const float4*>(bin + (size_t)row0 * HASHLEN);
#pragma unroll
    for (int it = 0; it < 4; ++it) {
      int idx = tid + FNT * it;
      int r = idx >> 4, k4 = idx & 15;
      float4 v = src[idx];
      uint32_t p0 = f2bf(v.x) | ((uint32_t)f2bf(v.y) << 16);
      uint32_t p1 = f2bf(v.z) | ((uint32_t)f2bf(v.w) << 16);
      int off = FSB_OFF + r * 128 + ((k4 * 8) ^ ((r & 7) << 4));
      *(uint32_t*)(lds + off) = p0;
      *(uint32_t*)(lds + off + 4) = p1;
    }
#pragma unroll
    for (int it = 0; it < 12; ++it) {
      int idx = tid + FNT * it;
      int n = idx >> 4, k4 = idx & 15;
      float4 v = make_float4(0.f, 0.f, 0.f, 0.f);
      if (n < HID) v = *(const float4*)(W_h + (size_t)n * HASHLEN + k4 * 4);
      uint32_t p0 = f2bf(v.x) | ((uint32_t)f2bf(v.y) << 16);
      uint32_t p1 = f2bf(v.z) | ((uint32_t)f2bf(v.w) << 16);
      int off = FSWH_OFF + n * 128 + ((k4 * 8) ^ ((n & 7) << 4));
      *(uint32_t*)(lds + off) = p0;
      *(uint32_t*)(lds + off + 4) = p1;
    }
  }
  __syncthreads();
  {
    bf16x8 a1[2];
#pragma unroll
    for (int s = 0; s < 2; ++s)
      a1[s] = *(const bf16x8*)(lds + FSB_OFF + (r0 + lane15) * 128 + ((s * 64 + lhi * 16) ^ swzb));
#pragma unroll
    for (int nt = 0; nt < 12; ++nt) {
      f32x4 acc = {0.f, 0.f, 0.f, 0.f};
#pragma unroll
      for (int s = 0; s < 2; ++s) {
        bf16x8 bf = *(const bf16x8*)(lds + FSWH_OFF + (nt * 16 + lane15) * 128 + ((s * 64 + lhi * 16) ^ swzb));
        acc = __builtin_amdgcn_mfma_f32_16x16x32_bf16(a1[s], bf, acc, 0, 0, 0);
      }
      int col = nt * 16 + lane15;
      float bias = (col < HID) ? b_h[col] : 0.0f;
#pragma unroll
      for (int q = 0; q < 4; ++q) {
        int row = r0 + lhi * 4 + q;
        float h = (col < HID) ? (acc[q] + bias) : 0.0f;
        *(uint16_t*)(lds + FSH_OFF + row * 384 + ((2 * col) ^ ((row & 7) << 4))) = f2bf(h);
      }
    }
  }
  __syncthreads();
  bf16x8 a2[6];
#pragma unroll
  for (int s = 0; s < 6; ++s)
    a2[s] = *(const bf16x8*)(lds + FSH_OFF + (r0 + lane15) * 384 + ((s * 64 + lhi * 16) ^ swzb));
  const int rowi = tid >> 3;
  const int tt8 = tid & 7;
  for (int ch = 0; ch < FNCH; ++ch) {
    const int t0 = ch * FCHT;
    const int ntc = (FTILE2 - t0 < FCHT) ? (FTILE2 - t0) : FCHT;
    if (rowi < ntc * 16) {
      int col = ch * 32 + rowi;
      bool cok = (col < OUT);
      const float* wm = W_mu + (size_t)col * HID;
      const float* wsg = W_sig + (size_t)col * HID;
#pragma unroll
      for (int it = 0; it < 12; ++it) {
        int k2 = tt8 + 8 * it;
        bool kok = cok && (k2 < 90);
        float2 vm = kok ? *(const float2*)(wm + k2 * 2) : make_float2(0.f, 0.f);
        float2 vs = kok ? *(const float2*)(wsg + k2 * 2) : make_float2(0.f, 0.f);
        int off = (k2 * 4) ^ ((rowi & 7) << 4);
        *(uint32_t*)(lds + FSWM_OFF + rowi * 384 + off) = f2bf(vm.x) | ((uint32_t)f2bf(vm.y) << 16);
        *(uint32_t*)(lds + FSWS_OFF + rowi * 384 + off) = f2bf(vs.x) | ((uint32_t)f2bf(vs.y) << 16);
      }
    }
    __syncthreads();
    for (int nt2 = 0; nt2 < ntc; ++nt2) {
      const int gt = t0 + nt2;
      const int crow = nt2 * 16 + lane15;
      f32x4 accM = {0.f, 0.f, 0.f, 0.f};
      f32x4 accS = {0.f, 0.f, 0.f, 0.f};
#pragma unroll
      for (int s = 0; s < 6; ++s) {
        int boff = (s * 64 + lhi * 16) ^ swzb;
        bf16x8 bm = *(const bf16x8*)(lds + FSWM_OFF + crow * 384 + boff);
        bf16x8 bs = *(const bf16x8*)(lds + FSWS_OFF + crow * 384 + boff);
        accM = __builtin_amdgcn_mfma_f32_16x16x32_bf16(a2[s], bm, accM, 0, 0, 0);
        accS = __builtin_amdgcn_mfma_f32_16x16x32_bf16(a2[s], bs, accS, 0, 0, 0);
      }
      const int col = gt * 16 + lane15;
      if (col < OUT) {
        const float bmu = b_mu[col];
        const float bsg = b_sig[col];
#pragma unroll
        for (int q = 0; q < 4; ++q) {
          int row = r0 + lhi * 4 + q;
          int gr = row0 + row;
          float mu = accM[q] + bmu;
          float sg = fabsf(accS[q] + bsg);
          uint32_t gi = (uint32_t)(gr * OUT + col);
          uint32_t bits = threefry_bits(gi);
          float eps = eps_from_bits(bits);
          out[(size_t)gr * OUT + col] = fmaf(sg, eps, mu);
        }
      }
    }
    __syncthreads();
  }
}

extern "C" void kernel_launch(void* const* d_in, const int* in_sizes, int n_in,
                              void* d_out, int out_size, void* d_ws, size_t ws_size,
                              hipStream_t stream) {
  const float* b     = (const float*)d_in[0];
  const float* W_h   = (const float*)d_in[2];
  const float* b_h   = (const float*)d_in[3];
  const float* W_mu  = (const float*)d_in[4];
  const float* b_mu  = (const float*)d_in[5];
  const float* W_sig = (const float*)d_in[6];
  const float* b_sig = (const float*)d_in[7];
  float* out = (float*)d_out;

  if (ws_size >= WS_NEEDED && d_ws != nullptr) {
    uint16_t* ws = (uint16_t*)d_ws;
    hipLaunchKernelGGL(prep_weights, dim3((TOT_FRAGS + 255) / 256), dim3(256), 0, stream,
                       W_h, W_mu, W_sig, ws);
    hipLaunchKernelGGL(fused_decoder, dim3(BATCH / BM), dim3(NT), 0, stream,
                       b, ws, b_h, b_mu, b_sig, out);
  } else {
    hipLaunchKernelGGL(fused_decoder_fb, dim3(BATCH / BM), dim3(FNT), 0, stream,
                       b, W_h, b_h, W_mu, b_mu, W_sig, b_sig, out);
  }
}

// Round 15
// 136.977 us; speedup vs baseline: 1.0908x; 1.0908x over previous
//
#include <hip/hip_runtime.h>
#include <stdint.h>

#define BATCH   131072
#define HASHLEN 64
#define HID     180
#define OUT     300

#define BM      64        // rows per block
#define NT      256       // 4 waves; each wave owns 16 rows
#define NTILE2  19        // ceil(300/16)

// fragment counts in ws
#define WH_FRAGS  (12 * 2 * 64)             // 1536
#define WM_FRAGS  (NTILE2 * 6 * 64)         // 7296
#define TOT_FRAGS (WH_FRAGS + 2 * WM_FRAGS) // 16128
#define WS_NEEDED ((size_t)TOT_FRAGS * 16)  // 258048 B

typedef short bf16x8 __attribute__((ext_vector_type(8)));
typedef float f32x4  __attribute__((ext_vector_type(4)));

// fast hw ops
#define FAST_SQRT(x) __builtin_amdgcn_sqrtf(x)   // v_sqrt_f32
#define ROTL(x, r) __builtin_amdgcn_alignbit((x), (x), 32u - (r))

// Threefry-2x32/20, key (0,42), counter (0,ctr), bits = x0^x1 (verified R0/R2).
__device__ __forceinline__ unsigned threefry_bits(unsigned ctr) {
  const unsigned ks0 = 0u;
  const unsigned ks1 = 42u;
  const unsigned ks2 = 0x1BD11BDAu ^ 0u ^ 42u;
  unsigned x0 = ks0;
  unsigned x1 = ctr + ks1;
#define TF_R(r) { x0 += x1; x1 = ROTL(x1, r); x1 ^= x0; }
  TF_R(13u) TF_R(15u) TF_R(26u) TF_R(6u)
  x0 += ks1; x1 += ks2 + 1u;
  TF_R(17u) TF_R(29u) TF_R(16u) TF_R(24u)
  x0 += ks2; x1 += ks0 + 2u;
  TF_R(13u) TF_R(15u) TF_R(26u) TF_R(6u)
  x0 += ks0; x1 += ks1 + 3u;
  TF_R(17u) TF_R(29u) TF_R(16u) TF_R(24u)
  x0 += ks1; x1 += ks2 + 4u;
  TF_R(13u) TF_R(15u) TF_R(26u) TF_R(6u)
  x0 += ks2; x1 += ks0 + 5u;
#undef TF_R
  return x0 ^ x1;
}

// sqrt(2)*erfinv(x), XLA-Giles polynomial in log2 domain (verified R5).
__device__ __forceinline__ float poly_low_sqrt2(float zz) {
  float p = 2.11772e-09f;
  p = fmaf(p, zz, 3.73196e-08f);
  p = fmaf(p, zz, -5.52613e-07f);
  p = fmaf(p, zz, -9.93702e-07f);
  p = fmaf(p, zz, 7.13551e-05f);
  p = fmaf(p, zz, -5.90464e-04f);
  p = fmaf(p, zz, -2.83858e-03f);
  p = fmaf(p, zz, 0.24177160f);
  p = fmaf(p, zz, 2.1233136f);
  return p;
}
__device__ __forceinline__ float poly_high_sqrt2(float v) {
  float p = -6.53600e-05f;
  p = fmaf(p, v, 3.95852e-05f);
  p = fmaf(p, v, 6.35506e-04f);
  p = fmaf(p, v, -2.07827e-03f);
  p = fmaf(p, v, 3.89984e-03f);
  p = fmaf(p, v, -6.22117e-03f);
  p = fmaf(p, v, 9.25254e-03f);
  p = fmaf(p, v, 1.1793807f);
  p = fmaf(p, v, 4.0064340f);
  return p;
}

// full eps from threefry bits (verified R5 path)
__device__ __forceinline__ float eps_from_bits(uint32_t bits) {
  float f = __uint_as_float((bits >> 9) | 0x3F800000u) - 1.0f;
  const float LO = -0.99999994f;
  float u = fmaxf(LO, fmaf(f, 2.0f, LO));
  float t = fmaf(-u, u, 1.0f);
  float z = -__log2f(t);
  float p = poly_low_sqrt2(z - 3.6067376f);
  if (__any(z >= 7.2134752f)) {
    float ph = poly_high_sqrt2(FAST_SQRT(z) - 3.6033669f);
    p = (z >= 7.2134752f) ? ph : p;
  }
  return p * u;
}

// fp32 -> bf16 round-to-nearest-even
__device__ __forceinline__ uint16_t f2bf(float f) {
  uint32_t u = __float_as_uint(f);
  return (uint16_t)((u + 0x7FFFu + ((u >> 16) & 1u)) >> 16);
}

// ---------------- pre-kernel: weights to MFMA fragment order ----------------
__global__ __launch_bounds__(256) void prep_weights(
    const float* __restrict__ W_h, const float* __restrict__ W_mu,
    const float* __restrict__ W_sig, uint16_t* __restrict__ ws)
{
  int f = blockIdx.x * 256 + threadIdx.x;
  if (f >= TOT_FRAGS) return;
  uint16_t vals[8];
  if (f < WH_FRAGS) {
    int nt = f >> 7, s = (f >> 6) & 1, l = f & 63;
    int row = nt * 16 + (l & 15);
    int k0  = s * 32 + (l >> 4) * 8;
#pragma unroll
    for (int j = 0; j < 8; ++j)
      vals[j] = (row < HID) ? f2bf(W_h[row * HASHLEN + k0 + j]) : (uint16_t)0;
  } else {
    int g = f - WH_FRAGS;
    const float* W = (g < WM_FRAGS) ? W_mu : W_sig;
    if (g >= WM_FRAGS) g -= WM_FRAGS;
    int gt = g / 384, s = (g >> 6) % 6, l = g & 63;
    int col = gt * 16 + (l & 15);
    int k0  = s * 32 + (l >> 4) * 8;
#pragma unroll
    for (int j = 0; j < 8; ++j) {
      int k = k0 + j;
      vals[j] = (col < OUT && k < HID) ? f2bf(W[col * HID + k]) : (uint16_t)0;
    }
  }
  uint16_t* dst = ws + (size_t)f * 8;
#pragma unroll
  for (int j = 0; j < 8; ++j) dst[j] = vals[j];
}

// epilogue over a PAIR of adjacent gt tiles: 8 outputs/lane, 8 threefry chains
__device__ __forceinline__ void epilogue8(
    f32x4 aM0, f32x4 aS0, f32x4 aM1, f32x4 aS1,
    f32x4 bm0, f32x4 bs0, f32x4 bm1, f32x4 bs1,
    uint32_t gi0, float* __restrict__ out)
{
  uint32_t bits[8];
#pragma unroll
  for (int j = 0; j < 8; ++j) {
    // cols: tile0 -> gi0+{0..3}, tile1 -> gi0+16+{0..3}
    uint32_t c = gi0 + (uint32_t)((j < 4) ? j : (12 + j));
    bits[j] = threefry_bits(c);
  }
  float xx[8], z[8], pl[8];
#pragma unroll
  for (int j = 0; j < 8; ++j) {
    float f = __uint_as_float((bits[j] >> 9) | 0x3F800000u) - 1.0f;
    const float LO = -0.99999994f;     // nextafter(-1, 0)
    float u = fmaxf(LO, fmaf(f, 2.0f, LO));
    xx[j] = u;
    float t = fmaf(-u, u, 1.0f);
    z[j] = -__log2f(t);                // v_log_f32
    pl[j] = poly_low_sqrt2(z[j] - 3.6067376f);
  }
#pragma unroll
  for (int j = 0; j < 8; ++j) {
    if (__any(z[j] >= 7.2134752f)) {
      float ph = poly_high_sqrt2(FAST_SQRT(z[j]) - 3.6033669f);
      pl[j] = (z[j] >= 7.2134752f) ? ph : pl[j];
    }
  }
  f32x4 r0, r1;
#pragma unroll
  for (int q = 0; q < 4; ++q) {
    r0[q] = fmaf(fabsf(aS0[q] + bs0[q]), pl[q] * xx[q],         aM0[q] + bm0[q]);
    r1[q] = fmaf(fabsf(aS1[q] + bs1[q]), pl[q + 4] * xx[q + 4], aM1[q] + bm1[q]);
  }
  *(f32x4*)(out + gi0)      = r0;
  *(f32x4*)(out + gi0 + 16) = r1;
}

// single-tile epilogue (tail)
__device__ __forceinline__ void epilogue4(
    f32x4 accM, f32x4 accS, f32x4 bm4, f32x4 bs4, uint32_t gi0,
    float* __restrict__ out)
{
  uint32_t bits[4];
#pragma unroll
  for (int q = 0; q < 4; ++q)
    bits[q] = threefry_bits(gi0 + (uint32_t)q);
  float xx[4], z[4], pl[4];
#pragma unroll
  for (int q = 0; q < 4; ++q) {
    float f = __uint_as_float((bits[q] >> 9) | 0x3F800000u) - 1.0f;
    const float LO = -0.99999994f;
    float u = fmaxf(LO, fmaf(f, 2.0f, LO));
    xx[q] = u;
    float t = fmaf(-u, u, 1.0f);
    z[q] = -__log2f(t);
    pl[q] = poly_low_sqrt2(z[q] - 3.6067376f);
  }
#pragma unroll
  for (int q = 0; q < 4; ++q) {
    if (__any(z[q] >= 7.2134752f)) {
      float ph = poly_high_sqrt2(FAST_SQRT(z[q]) - 3.6033669f);
      pl[q] = (z[q] >= 7.2134752f) ? ph : pl[q];
    }
  }
  f32x4 res;
#pragma unroll
  for (int q = 0; q < 4; ++q) {
    float mu  = accM[q] + bm4[q];
    float sg  = fabsf(accS[q] + bs4[q]);
    res[q] = fmaf(sg, pl[q] * xx[q], mu);
  }
  *(f32x4*)(out + gi0) = res;
}

// ---------------- main fused kernel (R12: pair-of-2 tiles, NT=256) ----------
__global__ __launch_bounds__(NT, 4) void fused_decoder(
    const float* __restrict__ bin,
    const uint16_t* __restrict__ ws,
    const float* __restrict__ b_h,
    const float* __restrict__ b_mu, const float* __restrict__ b_sig,
    float* __restrict__ out)
{
  __shared__ unsigned char lds[BM * 384];   // h tile [64][192] bf16, swizzled

  const int tid    = threadIdx.x;
  const int l      = tid & 63;
  const int w      = tid >> 6;
  const int lane15 = l & 15;
  const int lhi    = l >> 4;
  const int swzb   = (lane15 & 7) << 4;
  const int row0   = blockIdx.x * BM;
  const int r0     = w * 16;

  const bf16x8* wsWh = (const bf16x8*)ws;
  const bf16x8* wsWm = (const bf16x8*)ws + WH_FRAGS;
  const bf16x8* wsWs = (const bf16x8*)ws + WH_FRAGS + WM_FRAGS;

  // ---------- GEMM1 (swapped): h^T = W_h @ b^T -> h tile (bf16, swizzled) --
  {
    const float* brow = bin + (size_t)(row0 + r0 + lane15) * HASHLEN;
    bf16x8 bfrag[2];
#pragma unroll
    for (int s = 0; s < 2; ++s) {
      float4 v0 = *(const float4*)(brow + s * 32 + lhi * 8);
      float4 v1 = *(const float4*)(brow + s * 32 + lhi * 8 + 4);
      bf16x8 a;
      a[0] = (short)f2bf(v0.x); a[1] = (short)f2bf(v0.y);
      a[2] = (short)f2bf(v0.z); a[3] = (short)f2bf(v0.w);
      a[4] = (short)f2bf(v1.x); a[5] = (short)f2bf(v1.y);
      a[6] = (short)f2bf(v1.z); a[7] = (short)f2bf(v1.w);
      bfrag[s] = a;
    }
    const int row = r0 + lane15;
#pragma unroll
    for (int nt = 0; nt < 12; ++nt) {
      f32x4 acc = {0.f, 0.f, 0.f, 0.f};
#pragma unroll
      for (int s = 0; s < 2; ++s)
        acc = __builtin_amdgcn_mfma_f32_16x16x32_bf16(wsWh[(nt * 2 + s) * 64 + l], bfrag[s], acc, 0, 0, 0);
      const int k0 = nt * 16 + lhi * 4;
      f32x4 bias = {0.f, 0.f, 0.f, 0.f};
      if (k0 <= HID - 4) bias = *(const f32x4*)(b_h + k0);
      const bool ok = (k0 < HID);             // quad-uniform (HID % 4 == 0)
      float h0 = ok ? (acc[0] + bias[0]) : 0.0f;
      float h1 = ok ? (acc[1] + bias[1]) : 0.0f;
      float h2 = ok ? (acc[2] + bias[2]) : 0.0f;
      float h3 = ok ? (acc[3] + bias[3]) : 0.0f;
      uint2 pk;
      pk.x = (uint32_t)f2bf(h0) | ((uint32_t)f2bf(h1) << 16);
      pk.y = (uint32_t)f2bf(h2) | ((uint32_t)f2bf(h3) << 16);
      *(uint2*)(lds + row * 384 + ((2 * k0) ^ swzb)) = pk;
    }
  }
  // no barrier: h tile is wave-private; same-wave LDS ops are in-order.

  bf16x8 a2[6];
#pragma unroll
  for (int s = 0; s < 6; ++s)
    a2[s] = *(const bf16x8*)(lds + (r0 + lane15) * 384 + ((s * 64 + lhi * 16) ^ swzb));

  // lane output: batch row = lane15-row, cols = gt*16 + lhi*4 + {0..3}
  const uint32_t idx0 = (uint32_t)((row0 + r0 + lane15) * OUT + lhi * 4);

  // ---------- GEMM2: 9 tile-pairs (gt 0..17), then tail gt=18 ----------
#pragma unroll 1
  for (int gp = 0; gp < 9; ++gp) {
    const int gt0 = gp * 2;
    const int gt1 = gt0 + 1;
    f32x4 aM0 = {0.f, 0.f, 0.f, 0.f};
    f32x4 aS0 = {0.f, 0.f, 0.f, 0.f};
    f32x4 aM1 = {0.f, 0.f, 0.f, 0.f};
    f32x4 aS1 = {0.f, 0.f, 0.f, 0.f};
#pragma unroll
    for (int s = 0; s < 6; ++s)
      aM0 = __builtin_amdgcn_mfma_f32_16x16x32_bf16(wsWm[(gt0 * 6 + s) * 64 + l], a2[s], aM0, 0, 0, 0);
#pragma unroll
    for (int s = 0; s < 6; ++s)
      aS0 = __builtin_amdgcn_mfma_f32_16x16x32_bf16(wsWs[(gt0 * 6 + s) * 64 + l], a2[s], aS0, 0, 0, 0);
#pragma unroll
    for (int s = 0; s < 6; ++s)
      aM1 = __builtin_amdgcn_mfma_f32_16x16x32_bf16(wsWm[(gt1 * 6 + s) * 64 + l], a2[s], aM1, 0, 0, 0);
#pragma unroll
    for (int s = 0; s < 6; ++s)
      aS1 = __builtin_amdgcn_mfma_f32_16x16x32_bf16(wsWs[(gt1 * 6 + s) * 64 + l], a2[s], aS1, 0, 0, 0);

    const int c0 = gt0 * 16 + lhi * 4;
    f32x4 bm0 = *(const f32x4*)(b_mu + c0);
    f32x4 bs0 = *(const f32x4*)(b_sig + c0);
    f32x4 bm1 = *(const f32x4*)(b_mu + c0 + 16);
    f32x4 bs1 = *(const f32x4*)(b_sig + c0 + 16);
    epilogue8(aM0, aS0, aM1, aS1, bm0, bs0, bm1, bs1,
              idx0 + (uint32_t)(gt0 * 16), out);
  }

  // tail tile gt=18: cols 288 + lhi*4 + q -> valid iff lhi < 3 (quad-uniform)
  {
    const int gt = NTILE2 - 1;
    f32x4 accM = {0.f, 0.f, 0.f, 0.f};
    f32x4 accS = {0.f, 0.f, 0.f, 0.f};
#pragma unroll
    for (int s = 0; s < 6; ++s) {
      accM = __builtin_amdgcn_mfma_f32_16x16x32_bf16(wsWm[(gt * 6 + s) * 64 + l], a2[s], accM, 0, 0, 0);
      accS = __builtin_amdgcn_mfma_f32_16x16x32_bf16(wsWs[(gt * 6 + s) * 64 + l], a2[s], accS, 0, 0, 0);
    }
    if (lhi < 3) {
      const int c0 = gt * 16 + lhi * 4;
      f32x4 bm4 = *(const f32x4*)(b_mu + c0);
      f32x4 bs4 = *(const f32x4*)(b_sig + c0);
      epilogue4(accM, accS, bm4, bs4, idx0 + (uint32_t)(gt * 16), out);
    }
  }
}

// ---------------- fallback (no ws): R2-proven path --------------------------
#define FTILE2  19
#define FCHT    2
#define FNCH    10
#define FSH_OFF   0
#define FSH_BYTES (64 * 384)
#define FU_OFF    FSH_BYTES
#define FSB_OFF   FU_OFF
#define FSWH_OFF  (FU_OFF + 8192)
#define FSWM_OFF  FU_OFF
#define FSWS_OFF  (FU_OFF + 12288)
#define FLDS_BYTES (FSH_BYTES + 32768)

__global__ __launch_bounds__(NT) void fused_decoder_fb(
    const float* __restrict__ bin,
    const float* __restrict__ W_h, const float* __restrict__ b_h,
    const float* __restrict__ W_mu, const float* __restrict__ b_mu,
    const float* __restrict__ W_sig, const float* __restrict__ b_sig,
    float* __restrict__ out)
{
  __shared__ unsigned char lds[FLDS_BYTES];
  const int tid = threadIdx.x;
  const int l = tid & 63, w = tid >> 6;
  const int lane15 = l & 15, lhi = l >> 4;
  const int swzb = (l & 7) << 4;
  const int row0 = blockIdx.x * BM;
  const int r0 = w * 16;
  {
    const float4* src = reinterpret_cast<const float4*>(bin + (size_t)row0 * HASHLEN);
#pragma unroll
    for (int it = 0; it < 4; ++it) {
      int idx = tid + NT * it;
      int r = idx >> 4, k4 = idx & 15;
      float4 v = src[idx];
      uint32_t p0 = f2bf(v.x) | ((uint32_t)f2bf(v.y) << 16);
      uint32_t p1 = f2bf(v.z) | ((uint32_t)f2bf(v.w) << 16);
      int off = FSB_OFF + r * 128 + ((k4 * 8) ^ ((r & 7) << 4));
      *(uint32_t*)(lds + off) = p0;
      *(uint32_t*)(lds + off + 4) = p1;
    }
#pragma unroll
    for (int it = 0; it < 12; ++it) {
      int idx = tid + NT * it;
      int n = idx >> 4, k4 = idx & 15;
      float4 v = make_float4(0.f, 0.f, 0.f, 0.f);
      if (n < HID) v = *(const float4*)(W_h + (size_t)n * HASHLEN + k4 * 4);
      uint32_t p0 = f2bf(v.x) | ((uint32_t)f2bf(v.y) << 16);
      uint32_t p1 = f2bf(v.z) | ((uint32_t)f2bf(v.w) << 16);
      int off = FSWH_OFF + n * 128 + ((k4 * 8) ^ ((n & 7) << 4));
      *(uint32_t*)(lds + off) = p0;
      *(uint32_t*)(lds + off + 4) = p1;
    }
  }
  __syncthreads();
  {
    bf16x8 a1[2];
#pragma unroll
    for (int s = 0; s < 2; ++s)
      a1[s] = *(const bf16x8*)(lds + FSB_OFF + (r0 + lane15) * 128 + ((s * 64 + lhi * 16) ^ swzb));
#pragma unroll
    for (int nt = 0; nt < 12; ++nt) {
      f32x4 acc = {0.f, 0.f, 0.f, 0.f};
#pragma unroll
      for (int s = 0; s < 2; ++s) {
        bf16x8 bf = *(const bf16x8*)(lds + FSWH_OFF + (nt * 16 + lane15) * 128 + ((s * 64 + lhi * 16) ^ swzb));
        acc = __builtin_amdgcn_mfma_f32_16x16x32_bf16(a1[s], bf, acc, 0, 0, 0);
      }
      int col = nt * 16 + lane15;
      float bias = (col < HID) ? b_h[col] : 0.0f;
#pragma unroll
      for (int q = 0; q < 4; ++q) {
        int row = r0 + lhi * 4 + q;
        float h = (col < HID) ? (acc[q] + bias) : 0.0f;
        *(uint16_t*)(lds + FSH_OFF + row * 384 + ((2 * col) ^ ((row & 7) << 4))) = f2bf(h);
      }
    }
  }
  __syncthreads();
  bf16x8 a2[6];
#pragma unroll
  for (int s = 0; s < 6; ++s)
    a2[s] = *(const bf16x8*)(lds + FSH_OFF + (r0 + lane15) * 384 + ((s * 64 + lhi * 16) ^ swzb));
  const int rowi = tid >> 3;
  const int tt8 = tid & 7;
  for (int ch = 0; ch < FNCH; ++ch) {
    const int t0 = ch * FCHT;
    const int ntc = (FTILE2 - t0 < FCHT) ? (FTILE2 - t0) : FCHT;
    if (rowi < ntc * 16) {
      int col = ch * 32 + rowi;
      bool cok = (col < OUT);
      const float* wm = W_mu + (size_t)col * HID;
      const float* wsg = W_sig + (size_t)col * HID;
#pragma unroll
      for (int it = 0; it < 12; ++it) {
        int k2 = tt8 + 8 * it;
        bool kok = cok && (k2 < 90);
        float2 vm = kok ? *(const float2*)(wm + k2 * 2) : make_float2(0.f, 0.f);
        float2 vs = kok ? *(const float2*)(wsg + k2 * 2) : make_float2(0.f, 0.f);
        int off = (k2 * 4) ^ ((rowi & 7) << 4);
        *(uint32_t*)(lds + FSWM_OFF + rowi * 384 + off) = f2bf(vm.x) | ((uint32_t)f2bf(vm.y) << 16);
        *(uint32_t*)(lds + FSWS_OFF + rowi * 384 + off) = f2bf(vs.x) | ((uint32_t)f2bf(vs.y) << 16);
      }
    }
    __syncthreads();
    for (int nt2 = 0; nt2 < ntc; ++nt2) {
      const int gt = t0 + nt2;
      const int crow = nt2 * 16 + lane15;
      f32x4 accM = {0.f, 0.f, 0.f, 0.f};
      f32x4 accS = {0.f, 0.f, 0.f, 0.f};
#pragma unroll
      for (int s = 0; s < 6; ++s) {
        int boff = (s * 64 + lhi * 16) ^ swzb;
        bf16x8 bm = *(const bf16x8*)(lds + FSWM_OFF + crow * 384 + boff);
        bf16x8 bs = *(const bf16x8*)(lds + FSWS_OFF + crow * 384 + boff);
        accM = __builtin_amdgcn_mfma_f32_16x16x32_bf16(a2[s], bm, accM, 0, 0, 0);
        accS = __builtin_amdgcn_mfma_f32_16x16x32_bf16(a2[s], bs, accS, 0, 0, 0);
      }
      const int col = gt * 16 + lane15;
      if (col < OUT) {
        const float bmu = b_mu[col];
        const float bsg = b_sig[col];
#pragma unroll
        for (int q = 0; q < 4; ++q) {
          int row = r0 + lhi * 4 + q;
          int gr = row0 + row;
          float mu = accM[q] + bmu;
          float sg = fabsf(accS[q] + bsg);
          uint32_t gi = (uint32_t)(gr * OUT + col);
          uint32_t bits = threefry_bits(gi);
          float eps = eps_from_bits(bits);
          out[(size_t)gr * OUT + col] = fmaf(sg, eps, mu);
        }
      }
    }
    __syncthreads();
  }
}

extern "C" void kernel_launch(void* const* d_in, const int* in_sizes, int n_in,
                              void* d_out, int out_size, void* d_ws, size_t ws_size,
                              hipStream_t stream) {
  const float* b     = (const float*)d_in[0];
  const float* W_h   = (const float*)d_in[2];
  const float* b_h   = (const float*)d_in[3];
  const float* W_mu  = (const float*)d_in[4];
  const float* b_mu  = (const float*)d_in[5];
  const float* W_sig = (const float*)d_in[6];
  const float* b_sig = (const float*)d_in[7];
  float* out = (float*)d_out;

  if (ws_size >= WS_NEEDED && d_ws != nullptr) {
    uint16_t* ws = (uint16_t*)d_ws;
    hipLaunchKernelGGL(prep_weights, dim3((TOT_FRAGS + 255) / 256), dim3(256), 0, stream,
                       W_h, W_mu, W_sig, ws);
    hipLaunchKernelGGL(fused_decoder, dim3(BATCH / BM), dim3(NT), 0, stream,
                       b, ws, b_h, b_mu, b_sig, out);
  } else {
    hipLaunchKernelGGL(fused_decoder_fb, dim3(BATCH / BM), dim3(NT), 0, stream,
                       b, W_h, b_h, W_mu, b_mu, W_sig, b_sig, out);
  }
}